// Round 3
// baseline (336.668 us; speedup 1.0000x reference)
//
#include <hip/hip_runtime.h>
#include <cmath>

// Problem constants: B=1024, D=2048, P=16384, TEMP=0.05, MOMENTUM=0.2
constexpr int B_N = 1024;
constexpr int D_N = 2048;
constexpr int P_N = 16384;
constexpr int TILE = 128;
constexpr int BK = 64;           // fp8 K-tile (2 MFMA k-steps per buffer)
constexpr int NT = P_N / TILE;   // 128 column tiles
constexpr int NIT = D_N / BK;    // 32 K iterations
#define TEMP_INV 20.0f
#define S_SCALE 16.0f            // storage rows pre-scaled into fp8 range
#define LOGIT_SCALE (TEMP_INV / S_SCALE)
#define MOM 0.2f

typedef __attribute__((ext_vector_type(4))) float floatx4;

__device__ __forceinline__ unsigned int pack4_fp8(float4 v) {
    unsigned int w = __builtin_amdgcn_cvt_pk_fp8_f32(v.x, v.y, 0, false);
    w = __builtin_amdgcn_cvt_pk_fp8_f32(v.z, v.w, w, true);
    return w;
}

__device__ __forceinline__ void gl_lds16(const void* g, void* l) {
    __builtin_amdgcn_global_load_lds(
        (const __attribute__((address_space(1))) void*)g,
        (__attribute__((address_space(3))) void*)l, 16, 0, 0);
}

// ---------------------------------------------------------------------------
// Streaming fp8 convert ONLY (copy moved into the GEMM).
// Chunks [0, S_ITER) = S (scale x16 into Sf8); [S_ITER, TOT_ITER) = X -> Xf8.
// ---------------------------------------------------------------------------
constexpr int S_F4 = P_N * D_N / 4;       // 8,388,608 float4s
constexpr int S_ITER = S_F4 / 1024;       // 8192 chunks
constexpr int X_F4 = B_N * D_N / 4;       // 524,288 float4s
constexpr int X_ITER = X_F4 / 1024;       // 512 chunks
constexpr int TOT_ITER = S_ITER + X_ITER; // 8704

__global__ __launch_bounds__(256) void stream_convert_kernel(
    const float* __restrict__ X, const float* __restrict__ S,
    unsigned char* __restrict__ Xf8, unsigned char* __restrict__ Sf8,
    float* __restrict__ out0) {
    const int t = threadIdx.x;
    if (blockIdx.x == 0 && t == 0) out0[0] = 0.f;
    for (int bi = blockIdx.x; bi < TOT_ITER; bi += gridDim.x) {
        if (bi < S_ITER) {
            const size_t base = (size_t)bi * 1024;
            const float4* s4 = (const float4*)S + base;
            unsigned int* q = (unsigned int*)Sf8 + base;
            float4 v[4];
#pragma unroll
            for (int j = 0; j < 4; ++j) v[j] = s4[t + j * 256];
#pragma unroll
            for (int j = 0; j < 4; ++j) {
                float4 w = make_float4(v[j].x * S_SCALE, v[j].y * S_SCALE,
                                       v[j].z * S_SCALE, v[j].w * S_SCALE);
                q[t + j * 256] = pack4_fp8(w);
            }
        } else {
            const size_t base = (size_t)(bi - S_ITER) * 1024;
            const float4* x4 = (const float4*)X + base;
            unsigned int* q = (unsigned int*)Xf8 + base;
#pragma unroll
            for (int j = 0; j < 4; ++j) q[t + j * 256] = pack4_fp8(x4[t + j * 256]);
        }
    }
}

// ---------------------------------------------------------------------------
// Aligned-shifted storage copy: S floats [32768b, 32768(b+1)) -> outF[1+...].
// outF+1 is 4B-misaligned, so stores are realigned to out-quad boundaries:
// quad at outF float 4m holds {S[4m-1], S[4m], S[4m+1], S[4m+2]} — the shifted
// element comes from the neighbor lane via __shfl_up (lane0 reloads scalar).
// Nontemporal on both sides: read-once stream, must not evict Sf8 from L2/L3.
// ---------------------------------------------------------------------------
__device__ __forceinline__ void copy_block_rows(
    const float* __restrict__ S, float* __restrict__ outF, int b) {
    const int t = threadIdx.x;
    const size_t fbase = (size_t)b * 32768;
    if (t < 3) {  // head: outF[1+fbase .. 1+fbase+3)
        float v = __builtin_nontemporal_load(S + fbase + t);
        __builtin_nontemporal_store(v, outF + 1 + fbase + t);
    } else if (t == 3) {  // tail: outF[fbase+32768] = S[fbase+32767]
        float v = __builtin_nontemporal_load(S + fbase + 32767);
        __builtin_nontemporal_store(v, outF + fbase + 32768);
    }
    const floatx4* Sq = (const floatx4*)S + (size_t)b * 8192;
    floatx4* Oq = (floatx4*)outF + (size_t)b * 8192;
#pragma unroll 4
    for (int k = t; k < 8191; k += 256) {
        floatx4 cur = __builtin_nontemporal_load(Sq + 1 + k);
        float pw = __shfl_up(cur[3], 1);
        if ((t & 63) == 0)
            pw = __builtin_nontemporal_load((const float*)(Sq + 1 + k) - 1);
        floatx4 o; o[0] = pw; o[1] = cur[0]; o[2] = cur[1]; o[3] = cur[2];
        __builtin_nontemporal_store(o, Oq + 1 + k);
    }
}

// ---------------------------------------------------------------------------
// Chain-walk EMA update (sequential duplicate semantics), 1024 blocks.
// Runs AFTER the gemm (which writes the storage copy). Also computes exact
// fp32 label logits ll[k] = dot(X[k], S_orig[l]) * 20 for every chain elem.
// ---------------------------------------------------------------------------
__global__ __launch_bounds__(256) void update_kernel(
    const float* __restrict__ X, const float* __restrict__ S,
    const int* __restrict__ labels, float* __restrict__ outS,
    float* __restrict__ ll) {
    __shared__ int sl[B_N];
    __shared__ unsigned long long mask[16];
    __shared__ float red[8];   // [0..3] = ss, [4..7] = dot
    __shared__ int s_found;
    const int j = blockIdx.x;
    const int t = threadIdx.x;
    for (int k = t; k < B_N; k += 256) sl[k] = labels[k];
    if (t == 0) s_found = 0;
    if (t < 16) mask[t] = 0ull;
    __syncthreads();
    const int l = sl[j];
    for (int u = 0; u < 4; ++u) {
        int k = u * 256 + t;
        if (k < j && sl[k] == l) s_found = 1;                  // benign race
        if (k > j && sl[k] == l) atomicOr(&mask[k >> 6], 1ull << (k & 63));
    }
    __syncthreads();
    if (s_found) return;  // uniform: a predecessor owns this chain

    const float4* s4 = (const float4*)(S + (size_t)l * D_N);
    float4 v0 = s4[t], v1 = s4[256 + t];
    float r[8]  = {v0.x, v0.y, v0.z, v0.w, v1.x, v1.y, v1.z, v1.w};
    float so[8] = {v0.x, v0.y, v0.z, v0.w, v1.x, v1.y, v1.z, v1.w};
    const int lane = t & 63, wv = t >> 6;
    int k = j;
    while (true) {
        const float4* x4 = (const float4*)(X + (size_t)k * D_N);
        float4 a0 = x4[t], a1 = x4[256 + t];
        float xr[8] = {a0.x, a0.y, a0.z, a0.w, a1.x, a1.y, a1.z, a1.w};
        float ss = 0.f, dt = 0.f;
#pragma unroll
        for (int u = 0; u < 8; ++u) {
            r[u] = MOM * r[u] + (1.f - MOM) * xr[u];
            ss += r[u] * r[u];
            dt += so[u] * xr[u];
        }
        for (int off = 32; off; off >>= 1) {
            ss += __shfl_xor(ss, off);
            dt += __shfl_xor(dt, off);
        }
        if (lane == 0) { red[wv] = ss; red[4 + wv] = dt; }
        __syncthreads();
        ss = red[0] + red[1] + red[2] + red[3];
        dt = red[4] + red[5] + red[6] + red[7];
        __syncthreads();
        if (t == 0) ll[k] = dt * TEMP_INV;
        float inv = 1.0f / sqrtf(ss);
#pragma unroll
        for (int u = 0; u < 8; ++u) r[u] *= inv;
        int nk = -1;
        int w0 = k >> 6;
        unsigned long long bb = (mask[w0] >> (k & 63)) >> 1;
        if (bb) nk = k + 1 + (int)__builtin_ctzll(bb);
        else {
            for (int w = w0 + 1; w < 16; ++w) {
                if (mask[w]) { nk = w * 64 + (int)__builtin_ctzll(mask[w]); break; }
            }
        }
        if (nk < 0) break;
        k = nk;
    }
    float4* o4 = (float4*)(outS + (size_t)l * D_N);
    o4[t] = make_float4(r[0], r[1], r[2], r[3]);
    o4[256 + t] = make_float4(r[4], r[5], r[6], r[7]);
}

// ---------------------------------------------------------------------------
// Per-row EMA update-or-copy (fallback path only: scratch lives in d_out).
// ---------------------------------------------------------------------------
__device__ __forceinline__ void row_update(
    const float* __restrict__ X, const int* __restrict__ labels,
    int p, int t, float4 v0, float4 v1, float* __restrict__ outS,
    unsigned long long* mask, float* red) {
    if (t < 16) mask[t] = 0ull;
    __syncthreads();
    for (int u = 0; u < 4; ++u) {
        int k = u * 256 + t;
        if (labels[k] == p) atomicOr(&mask[k >> 6], 1ull << (k & 63));
    }
    __syncthreads();
    unsigned long long any = 0;
    for (int w = 0; w < 16; ++w) any |= mask[w];
    float4* o4 = (float4*)(outS + (size_t)p * D_N);
    if (!any) {  // uniform: plain copy
        o4[t] = v0; o4[256 + t] = v1;
        return;
    }
    float r[8] = {v0.x, v0.y, v0.z, v0.w, v1.x, v1.y, v1.z, v1.w};
    int k = -1;
    for (int w = 0; w < 16; ++w) {
        if (mask[w]) { k = w * 64 + (int)__builtin_ctzll(mask[w]); break; }
    }
    const int lane = t & 63, wv = t >> 6;
    while (k >= 0) {
        const float4* xk = (const float4*)(X + (size_t)k * D_N);
        float4 a0 = xk[t], a1 = xk[256 + t];
        float xr[8] = {a0.x, a0.y, a0.z, a0.w, a1.x, a1.y, a1.z, a1.w};
        float ss = 0.f;
#pragma unroll
        for (int u = 0; u < 8; ++u) {
            r[u] = MOM * r[u] + (1.f - MOM) * xr[u];
            ss += r[u] * r[u];
        }
        for (int off = 32; off; off >>= 1) ss += __shfl_xor(ss, off);
        if (lane == 0) red[wv] = ss;
        __syncthreads();
        ss = red[0] + red[1] + red[2] + red[3];
        __syncthreads();
        float inv = 1.0f / sqrtf(ss);
#pragma unroll
        for (int u = 0; u < 8; ++u) r[u] *= inv;
        int nk = -1;
        int w0 = k >> 6;
        unsigned long long bb = (mask[w0] >> (k & 63)) >> 1;
        if (bb) nk = k + 1 + (int)__builtin_ctzll(bb);
        else {
            for (int w = w0 + 1; w < 16; ++w) {
                if (mask[w]) { nk = w * 64 + (int)__builtin_ctzll(mask[w]); break; }
            }
        }
        k = nk;
    }
    o4[t] = make_float4(r[0], r[1], r[2], r[3]);
    o4[256 + t] = make_float4(r[4], r[5], r[6], r[7]);
}

__global__ __launch_bounds__(256) void update_copy_kernel(
    const float* __restrict__ X, const float* __restrict__ S,
    const int* __restrict__ labels, float* __restrict__ outS) {
    __shared__ unsigned long long mask[16];
    __shared__ float red[4];
    const int p = blockIdx.x;
    const int t = threadIdx.x;
    const float4* s4 = (const float4*)(S + (size_t)p * D_N);
    float4 v0 = s4[t], v1 = s4[256 + t];
    row_update(X, labels, p, t, v0, v1, outS, mask, red);
}

// ---------------------------------------------------------------------------
// fp8 MFMA GEMM (verified depth-2 counted-vmcnt pipeline + swizzle) with the
// fp32 storage copy folded in. Parity-stagger: even blocks copy BEFORE the
// K-loop, odd blocks AFTER — copy (HBM) phases overlap compute (MFMA) phases
// across co-resident blocks; the GEMM's HBM pipe is otherwise idle.
// ---------------------------------------------------------------------------
__global__ __launch_bounds__(256, 4) void gemm_softmax_kernel(
    const unsigned char* __restrict__ Xf8, const unsigned char* __restrict__ Sf8,
    const float* __restrict__ Sfull, float* __restrict__ outF,
    float* __restrict__ part_max, float* __restrict__ part_sum) {
    __shared__ alignas(16) unsigned char sA[2][TILE * BK];   // 2 x 8 KB
    __shared__ alignas(16) unsigned char sB[2][TILE * BK];   // 2 x 8 KB
    __shared__ float pmax[2][TILE];
    __shared__ float psum[2][TILE];

    const int t = threadIdx.x;
    const int b = blockIdx.x;
    const bool do_copy = (outF != nullptr);
    if (do_copy && !(b & 1)) copy_block_rows(Sfull, outF, b);

    const int xcd = b & 7;
    const int s = b >> 3;
    const int bm = s >> 4;                 // 0..7
    const int bn = (xcd << 4) | (s & 15);  // 0..127
    const int m0 = bm * TILE;
    const int n0 = bn * TILE;

    const int lane = t & 63;
    const int wave = t >> 6;
    const int wm = (wave & 1) * 64;
    const int wn = (wave >> 1) * 64;
    const int frow = lane & 15;
    const int q = lane >> 4;               // k-group 0..3 (8 bytes each)

    const int r0 = t >> 2, r1 = (t + 256) >> 2;
    const int sc0 = ((t & 3) ^ ((r0 & 3) ^ ((r0 >> 2) & 3))) << 4;
    const int sc1 = ((t & 3) ^ ((r1 & 3) ^ ((r1 >> 2) & 3))) << 4;
    const size_t rowA0 = (size_t)(m0 + r0) * D_N + sc0;
    const size_t rowA1 = (size_t)(m0 + r1) * D_N + sc1;
    const size_t rowB0 = (size_t)(n0 + r0) * D_N + sc0;
    const size_t rowB1 = (size_t)(n0 + r1) * D_N + sc1;

#define STAGE(bi, kt) do { const int kof = (kt) * BK;                 \
        gl_lds16(Xf8 + rowA0 + kof, &sA[bi][t * 16]);                 \
        gl_lds16(Xf8 + rowA1 + kof, &sA[bi][(t + 256) * 16]);         \
        gl_lds16(Sf8 + rowB0 + kof, &sB[bi][t * 16]);                 \
        gl_lds16(Sf8 + rowB1 + kof, &sB[bi][(t + 256) * 16]); } while (0)

    const int gswz = (frow & 3) ^ (frow >> 2);
    const int half = (q & 1) * 8;
    const int l0 = q >> 1;
    const int cof0 = (((l0) ^ gswz) << 4) + half;
    const int cof1 = (((l0 | 2) ^ gswz) << 4) + half;
    int aoffs[4], boffs[4];
#pragma unroll
    for (int i = 0; i < 4; ++i) aoffs[i] = (wm + i * 16 + frow) * BK;
#pragma unroll
    for (int j = 0; j < 4; ++j) boffs[j] = (wn + j * 16 + frow) * BK;

    floatx4 acc[4][4];
#pragma unroll
    for (int i = 0; i < 4; ++i)
#pragma unroll
        for (int j = 0; j < 4; ++j)
            acc[i][j] = floatx4{0.f, 0.f, 0.f, 0.f};

    STAGE(0, 0);
    STAGE(1, 1);
    int cur = 0;
    for (int it = 0; it < NIT; ++it) {
        if (it < NIT - 1) asm volatile("s_waitcnt vmcnt(4)" ::: "memory");
        else              asm volatile("s_waitcnt vmcnt(0)" ::: "memory");
        __builtin_amdgcn_s_barrier();      // all waves' tile `it` staged
        const unsigned char* pa = &sA[cur][0];
        const unsigned char* pb = &sB[cur][0];
#pragma unroll
        for (int kk = 0; kk < 2; ++kk) {
            const int cof = kk ? cof1 : cof0;
            long long af[4], bf[4];
#pragma unroll
            for (int i = 0; i < 4; ++i)
                af[i] = *(const long long*)(pa + aoffs[i] + cof);
#pragma unroll
            for (int j = 0; j < 4; ++j)
                bf[j] = *(const long long*)(pb + boffs[j] + cof);
#pragma unroll
            for (int i = 0; i < 4; ++i)
#pragma unroll
                for (int j = 0; j < 4; ++j)
                    acc[i][j] = __builtin_amdgcn_mfma_f32_16x16x32_fp8_fp8(
                        af[i], bf[j], acc[i][j], 0, 0, 0);
        }
        __builtin_amdgcn_sched_barrier(0); // pin reads before the barrier
        __builtin_amdgcn_s_barrier();      // all waves done reading buf[cur]
        if (it + 2 < NIT) STAGE(cur, it + 2);
        cur ^= 1;
    }
#undef STAGE

    // Epilogue: per-row max/sumexp over this block's 128 columns.
    float lmax[4][4], lsum[4][4];
    for (int i = 0; i < 4; i++) {
        for (int r = 0; r < 4; r++) {
            float m = -INFINITY;
            for (int j = 0; j < 4; j++) m = fmaxf(m, acc[i][j][r] * LOGIT_SCALE);
            for (int off = 1; off < 16; off <<= 1) m = fmaxf(m, __shfl_xor(m, off));
            float s2 = 0.f;
            for (int j = 0; j < 4; j++) s2 += __expf(acc[i][j][r] * LOGIT_SCALE - m);
            for (int off = 1; off < 16; off <<= 1) s2 += __shfl_xor(s2, off);
            lmax[i][r] = m; lsum[i][r] = s2;
        }
    }
    if ((lane & 15) == 0) {
        int lg = lane >> 4;
        for (int i = 0; i < 4; i++)
            for (int r = 0; r < 4; r++) {
                int row = wm + i * 16 + lg * 4 + r;
                pmax[wave >> 1][row] = lmax[i][r];
                psum[wave >> 1][row] = lsum[i][r];
            }
    }
    __syncthreads();
    if (t < TILE) {
        float ma = pmax[0][t], mb = pmax[1][t];
        float M = fmaxf(ma, mb);
        float Sv = psum[0][t] * __expf(ma - M) + psum[1][t] * __expf(mb - M);
        int grow = m0 + t;
        part_max[(size_t)grow * NT + bn] = M;
        part_sum[(size_t)grow * NT + bn] = Sv;
    }

    if (do_copy && (b & 1)) copy_block_rows(Sfull, outF, b);
}

// ---------------------------------------------------------------------------
// Loss: one wave per row. Label logit from ll[] (ws path) or exact gather-dot
// (fallback). LSE over the 128 tile partials + mean-NLL atomicAdd.
// ---------------------------------------------------------------------------
__global__ __launch_bounds__(256) void loss_kernel(
    const float* __restrict__ X, const float* __restrict__ S,
    const int* __restrict__ labels,
    const float* __restrict__ part_max, const float* __restrict__ part_sum,
    const float* __restrict__ ll_in, float* __restrict__ out0) {
    const int wave = threadIdx.x >> 6, lane = threadIdx.x & 63;
    const int row = blockIdx.x * 4 + wave;
    float ll;
    if (ll_in) {
        ll = ll_in[row];
    } else {
        const float4* x4 = (const float4*)(X + (size_t)row * D_N);
        const float4* s4 = (const float4*)(S + (size_t)labels[row] * D_N);
        float acc = 0.f;
        for (int k = lane; k < D_N / 4; k += 64) {
            float4 a = x4[k], bb = s4[k];
            acc += a.x * bb.x + a.y * bb.y + a.z * bb.z + a.w * bb.w;
        }
        for (int off = 32; off; off >>= 1) acc += __shfl_xor(acc, off);
        ll = acc * TEMP_INV;
    }
    const float* pm = part_max + (size_t)row * NT;
    const float* ps = part_sum + (size_t)row * NT;
    float m1 = pm[lane], m2 = pm[lane + 64];
    float M = fmaxf(m1, m2);
    for (int off = 32; off; off >>= 1) M = fmaxf(M, __shfl_xor(M, off));
    float Sv = ps[lane] * __expf(m1 - M) + ps[lane + 64] * __expf(m2 - M);
    for (int off = 32; off; off >>= 1) Sv += __shfl_xor(Sv, off);
    float v = ll - (M + __logf(Sv));
    __shared__ float red[4];
    if (lane == 0) red[wave] = v;
    __syncthreads();
    if (threadIdx.x == 0)
        atomicAdd(out0, -(red[0] + red[1] + red[2] + red[3]) * (1.0f / (float)B_N));
}

extern "C" void kernel_launch(void* const* d_in, const int* in_sizes, int n_in,
                              void* d_out, int out_size, void* d_ws, size_t ws_size,
                              hipStream_t stream) {
    const float* X = (const float*)d_in[0];       // (1024, 2048)
    const float* S = (const float*)d_in[1];       // (16384, 2048)
    const int* labels = (const int*)d_in[4];      // abs_proxy_labels (1024)
    float* out = (float*)d_out;                   // [loss, new_storage...]

    const size_t sf8_bytes = (size_t)P_N * D_N;            // 33,554,432
    const size_t xf8_bytes = (size_t)B_N * D_N;            //  2,097,152
    const size_t need = sf8_bytes + xf8_bytes + (size_t)B_N * NT * 8
                        + (size_t)B_N * 4 + 64;
    const bool use_ws = (ws_size >= need);

    unsigned char* scratch = use_ws ? (unsigned char*)d_ws
                                    : (unsigned char*)d_out + 16;
    unsigned char* Sf8 = scratch;
    unsigned char* Xf8 = scratch + sf8_bytes;
    float* part_max = (float*)(Xf8 + xf8_bytes);
    float* part_sum = part_max + (size_t)B_N * NT;
    float* ll = part_sum + (size_t)B_N * NT;

    // 1. Streaming fp8 convert (no copy; S lands in L3 for the gemm copy).
    stream_convert_kernel<<<2048, 256, 0, stream>>>(X, S, Xf8, Sf8, out);
    // 2. fp8 GEMM + softmax partials + parity-staggered fp32 storage copy.
    gemm_softmax_kernel<<<1024, 256, 0, stream>>>(
        Xf8, Sf8, S, use_ws ? out : nullptr, part_max, part_sum);
    // 3. Chain-walk EMA update (overwrites copied rows); computes ll.
    if (use_ws)
        update_kernel<<<B_N, 256, 0, stream>>>(X, S, labels, out + 1, ll);
    // 4. LSE + mean-NLL.
    loss_kernel<<<256, 256, 0, stream>>>(X, S, labels, part_max, part_sum,
                                         use_ws ? ll : nullptr, out);
    if (!use_ws)  // scratch lived inside out: write storage rows now
        update_copy_kernel<<<P_N, 256, 0, stream>>>(X, S, labels, out + 1);
}

// Round 4
// 321.254 us; speedup vs baseline: 1.0480x; 1.0480x over previous
//
#include <hip/hip_runtime.h>
#include <cmath>

// Problem constants: B=1024, D=2048, P=16384, TEMP=0.05, MOMENTUM=0.2
constexpr int B_N = 1024;
constexpr int D_N = 2048;
constexpr int P_N = 16384;
constexpr int TILE = 128;
constexpr int BK = 64;           // fp8 K-tile (2 MFMA k-steps per buffer)
constexpr int NT = P_N / TILE;   // 128 column tiles
constexpr int NIT = D_N / BK;    // 32 K iterations
#define TEMP_INV 20.0f
#define S_SCALE 16.0f            // storage rows pre-scaled into fp8 range
#define LOGIT_SCALE (TEMP_INV / S_SCALE)
#define MOM 0.2f

typedef __attribute__((ext_vector_type(4))) float floatx4;

__device__ __forceinline__ unsigned int pack4_fp8(float4 v) {
    unsigned int w = __builtin_amdgcn_cvt_pk_fp8_f32(v.x, v.y, 0, false);
    w = __builtin_amdgcn_cvt_pk_fp8_f32(v.z, v.w, w, true);
    return w;
}

__device__ __forceinline__ void gl_lds16(const void* g, void* l) {
    __builtin_amdgcn_global_load_lds(
        (const __attribute__((address_space(1))) void*)g,
        (__attribute__((address_space(3))) void*)l, 16, 0, 0);
}

// ---------------------------------------------------------------------------
// Streaming fp8 convert + ALIGNED-store fp32 copy.
// Copy realignment: out[1+s] = S[s], so out-quad q (16B-aligned) holds
// {S[4q-1], S[4q], S[4q+1], S[4q+2]}. Lane L (holding S-quad q) builds it
// with __shfl_up for the shifted element; lane 0 of each wave reloads one
// scalar (L1 hit). Head (out[1..3]) and tail (out[4*S_F4]) are scalar.
// Copy stores nontemporal (write-once; keep Sf8 L3-resident). S loads are
// NORMAL loads — S is L3-resident (round-3 lesson: nt loads forced HBM).
// Chunks [0, S_ITER) = S (scale x16 -> Sf8, + copy); rest = X -> Xf8.
// ---------------------------------------------------------------------------
constexpr int S_F4 = P_N * D_N / 4;       // 8,388,608 float4s
constexpr int S_ITER = S_F4 / 1024;       // 8192 chunks
constexpr int X_F4 = B_N * D_N / 4;       // 524,288 float4s
constexpr int X_ITER = X_F4 / 1024;       // 512 chunks
constexpr int TOT_ITER = S_ITER + X_ITER; // 8704

__global__ __launch_bounds__(256) void stream_convert_kernel(
    const float* __restrict__ X, const float* __restrict__ S,
    unsigned char* __restrict__ Xf8, unsigned char* __restrict__ Sf8,
    float* __restrict__ out0, float* __restrict__ outF) {
    const int t = threadIdx.x;
    if (blockIdx.x == 0 && t == 0) out0[0] = 0.f;
    for (int bi = blockIdx.x; bi < TOT_ITER; bi += gridDim.x) {
        if (bi < S_ITER) {
            const size_t qbase = (size_t)bi * 1024;   // S-quad index base
            const float4* s4 = (const float4*)S + qbase;
            unsigned int* qout = (unsigned int*)Sf8 + qbase;
            float4 v[4];
#pragma unroll
            for (int j = 0; j < 4; ++j) v[j] = s4[t + j * 256];
            if (outF) {
                floatx4* oq = (floatx4*)outF;
#pragma unroll
                for (int j = 0; j < 4; ++j) {
                    const size_t q = qbase + t + (size_t)j * 256;
                    float pw = __shfl_up(v[j].w, 1);
                    if ((t & 63) == 0 && q > 0) pw = S[4 * q - 1];
                    floatx4 o;
                    o[0] = pw; o[1] = v[j].x; o[2] = v[j].y; o[3] = v[j].z;
                    if (q > 0) __builtin_nontemporal_store(o, oq + q);
                    else {  // head: out[1..3] only (out[0] is the loss slot)
                        __builtin_nontemporal_store(v[j].x, outF + 1);
                        __builtin_nontemporal_store(v[j].y, outF + 2);
                        __builtin_nontemporal_store(v[j].z, outF + 3);
                    }
                    if (q == (size_t)S_F4 - 1)  // tail: out[4*S_F4] = S[last]
                        __builtin_nontemporal_store(v[j].w,
                                                    outF + (size_t)4 * S_F4);
                }
            }
#pragma unroll
            for (int j = 0; j < 4; ++j) {
                float4 w = make_float4(v[j].x * S_SCALE, v[j].y * S_SCALE,
                                       v[j].z * S_SCALE, v[j].w * S_SCALE);
                qout[t + j * 256] = pack4_fp8(w);
            }
        } else {
            const size_t base = (size_t)(bi - S_ITER) * 1024;
            const float4* x4 = (const float4*)X + base;
            unsigned int* qx = (unsigned int*)Xf8 + base;
#pragma unroll
            for (int j = 0; j < 4; ++j) qx[t + j * 256] = pack4_fp8(x4[t + j * 256]);
        }
    }
}

// ---------------------------------------------------------------------------
// Chain-walk EMA update (sequential duplicate semantics), 1024 blocks.
// Runs AFTER the convert (which wrote the storage copy); overwrites the
// labeled rows. Also computes exact fp32 label logits
// ll[k] = dot(X[k], S_orig[l]) * 20 for every chain element k.
// ---------------------------------------------------------------------------
__global__ __launch_bounds__(256) void update_kernel(
    const float* __restrict__ X, const float* __restrict__ S,
    const int* __restrict__ labels, float* __restrict__ outS,
    float* __restrict__ ll) {
    __shared__ int sl[B_N];
    __shared__ unsigned long long mask[16];
    __shared__ float red[8];   // [0..3] = ss, [4..7] = dot
    __shared__ int s_found;
    const int j = blockIdx.x;
    const int t = threadIdx.x;
    for (int k = t; k < B_N; k += 256) sl[k] = labels[k];
    if (t == 0) s_found = 0;
    if (t < 16) mask[t] = 0ull;
    __syncthreads();
    const int l = sl[j];
    for (int u = 0; u < 4; ++u) {
        int k = u * 256 + t;
        if (k < j && sl[k] == l) s_found = 1;                  // benign race
        if (k > j && sl[k] == l) atomicOr(&mask[k >> 6], 1ull << (k & 63));
    }
    __syncthreads();
    if (s_found) return;  // uniform: a predecessor owns this chain

    const float4* s4 = (const float4*)(S + (size_t)l * D_N);
    float4 v0 = s4[t], v1 = s4[256 + t];
    float r[8]  = {v0.x, v0.y, v0.z, v0.w, v1.x, v1.y, v1.z, v1.w};
    float so[8] = {v0.x, v0.y, v0.z, v0.w, v1.x, v1.y, v1.z, v1.w};
    const int lane = t & 63, wv = t >> 6;
    int k = j;
    while (true) {
        const float4* x4 = (const float4*)(X + (size_t)k * D_N);
        float4 a0 = x4[t], a1 = x4[256 + t];
        float xr[8] = {a0.x, a0.y, a0.z, a0.w, a1.x, a1.y, a1.z, a1.w};
        float ss = 0.f, dt = 0.f;
#pragma unroll
        for (int u = 0; u < 8; ++u) {
            r[u] = MOM * r[u] + (1.f - MOM) * xr[u];
            ss += r[u] * r[u];
            dt += so[u] * xr[u];
        }
        for (int off = 32; off; off >>= 1) {
            ss += __shfl_xor(ss, off);
            dt += __shfl_xor(dt, off);
        }
        if (lane == 0) { red[wv] = ss; red[4 + wv] = dt; }
        __syncthreads();
        ss = red[0] + red[1] + red[2] + red[3];
        dt = red[4] + red[5] + red[6] + red[7];
        __syncthreads();
        if (t == 0) ll[k] = dt * TEMP_INV;
        float inv = 1.0f / sqrtf(ss);
#pragma unroll
        for (int u = 0; u < 8; ++u) r[u] *= inv;
        int nk = -1;
        int w0 = k >> 6;
        unsigned long long bb = (mask[w0] >> (k & 63)) >> 1;
        if (bb) nk = k + 1 + (int)__builtin_ctzll(bb);
        else {
            for (int w = w0 + 1; w < 16; ++w) {
                if (mask[w]) { nk = w * 64 + (int)__builtin_ctzll(mask[w]); break; }
            }
        }
        if (nk < 0) break;
        k = nk;
    }
    float4* o4 = (float4*)(outS + (size_t)l * D_N);
    o4[t] = make_float4(r[0], r[1], r[2], r[3]);
    o4[256 + t] = make_float4(r[4], r[5], r[6], r[7]);
}

// ---------------------------------------------------------------------------
// Per-row EMA update-or-copy (fallback path only: scratch lives in d_out).
// ---------------------------------------------------------------------------
__device__ __forceinline__ void row_update(
    const float* __restrict__ X, const int* __restrict__ labels,
    int p, int t, float4 v0, float4 v1, float* __restrict__ outS,
    unsigned long long* mask, float* red) {
    if (t < 16) mask[t] = 0ull;
    __syncthreads();
    for (int u = 0; u < 4; ++u) {
        int k = u * 256 + t;
        if (labels[k] == p) atomicOr(&mask[k >> 6], 1ull << (k & 63));
    }
    __syncthreads();
    unsigned long long any = 0;
    for (int w = 0; w < 16; ++w) any |= mask[w];
    float4* o4 = (float4*)(outS + (size_t)p * D_N);
    if (!any) {  // uniform: plain copy
        o4[t] = v0; o4[256 + t] = v1;
        return;
    }
    float r[8] = {v0.x, v0.y, v0.z, v0.w, v1.x, v1.y, v1.z, v1.w};
    int k = -1;
    for (int w = 0; w < 16; ++w) {
        if (mask[w]) { k = w * 64 + (int)__builtin_ctzll(mask[w]); break; }
    }
    const int lane = t & 63, wv = t >> 6;
    while (k >= 0) {
        const float4* xk = (const float4*)(X + (size_t)k * D_N);
        float4 a0 = xk[t], a1 = xk[256 + t];
        float xr[8] = {a0.x, a0.y, a0.z, a0.w, a1.x, a1.y, a1.z, a1.w};
        float ss = 0.f;
#pragma unroll
        for (int u = 0; u < 8; ++u) {
            r[u] = MOM * r[u] + (1.f - MOM) * xr[u];
            ss += r[u] * r[u];
        }
        for (int off = 32; off; off >>= 1) ss += __shfl_xor(ss, off);
        if (lane == 0) red[wv] = ss;
        __syncthreads();
        ss = red[0] + red[1] + red[2] + red[3];
        __syncthreads();
        float inv = 1.0f / sqrtf(ss);
#pragma unroll
        for (int u = 0; u < 8; ++u) r[u] *= inv;
        int nk = -1;
        int w0 = k >> 6;
        unsigned long long bb = (mask[w0] >> (k & 63)) >> 1;
        if (bb) nk = k + 1 + (int)__builtin_ctzll(bb);
        else {
            for (int w = w0 + 1; w < 16; ++w) {
                if (mask[w]) { nk = w * 64 + (int)__builtin_ctzll(mask[w]); break; }
            }
        }
        k = nk;
    }
    o4[t] = make_float4(r[0], r[1], r[2], r[3]);
    o4[256 + t] = make_float4(r[4], r[5], r[6], r[7]);
}

__global__ __launch_bounds__(256) void update_copy_kernel(
    const float* __restrict__ X, const float* __restrict__ S,
    const int* __restrict__ labels, float* __restrict__ outS) {
    __shared__ unsigned long long mask[16];
    __shared__ float red[4];
    const int p = blockIdx.x;
    const int t = threadIdx.x;
    const float4* s4 = (const float4*)(S + (size_t)p * D_N);
    float4 v0 = s4[t], v1 = s4[256 + t];
    row_update(X, labels, p, t, v0, v1, outS, mask, red);
}

// ---------------------------------------------------------------------------
// fp8 MFMA GEMM, depth-2 counted-vmcnt pipeline + 16B-chunk XOR swizzle.
// (Reverted to the verified round-2 form: no fused copy, no S reads.)
// ---------------------------------------------------------------------------
__global__ __launch_bounds__(256, 4) void gemm_softmax_kernel(
    const unsigned char* __restrict__ Xf8, const unsigned char* __restrict__ Sf8,
    float* __restrict__ part_max, float* __restrict__ part_sum) {
    __shared__ alignas(16) unsigned char sA[2][TILE * BK];   // 2 x 8 KB
    __shared__ alignas(16) unsigned char sB[2][TILE * BK];   // 2 x 8 KB
    __shared__ float pmax[2][TILE];
    __shared__ float psum[2][TILE];

    const int t = threadIdx.x;
    const int b = blockIdx.x;
    const int xcd = b & 7;
    const int s = b >> 3;
    const int bm = s >> 4;                 // 0..7
    const int bn = (xcd << 4) | (s & 15);  // 0..127
    const int m0 = bm * TILE;
    const int n0 = bn * TILE;

    const int lane = t & 63;
    const int wave = t >> 6;
    const int wm = (wave & 1) * 64;
    const int wn = (wave >> 1) * 64;
    const int frow = lane & 15;
    const int q = lane >> 4;               // k-group 0..3 (8 bytes each)

    const int r0 = t >> 2, r1 = (t + 256) >> 2;
    const int sc0 = ((t & 3) ^ ((r0 & 3) ^ ((r0 >> 2) & 3))) << 4;
    const int sc1 = ((t & 3) ^ ((r1 & 3) ^ ((r1 >> 2) & 3))) << 4;
    const size_t rowA0 = (size_t)(m0 + r0) * D_N + sc0;
    const size_t rowA1 = (size_t)(m0 + r1) * D_N + sc1;
    const size_t rowB0 = (size_t)(n0 + r0) * D_N + sc0;
    const size_t rowB1 = (size_t)(n0 + r1) * D_N + sc1;

#define STAGE(bi, kt) do { const int kof = (kt) * BK;                 \
        gl_lds16(Xf8 + rowA0 + kof, &sA[bi][t * 16]);                 \
        gl_lds16(Xf8 + rowA1 + kof, &sA[bi][(t + 256) * 16]);         \
        gl_lds16(Sf8 + rowB0 + kof, &sB[bi][t * 16]);                 \
        gl_lds16(Sf8 + rowB1 + kof, &sB[bi][(t + 256) * 16]); } while (0)

    const int gswz = (frow & 3) ^ (frow >> 2);
    const int half = (q & 1) * 8;
    const int l0 = q >> 1;
    const int cof0 = (((l0) ^ gswz) << 4) + half;
    const int cof1 = (((l0 | 2) ^ gswz) << 4) + half;
    int aoffs[4], boffs[4];
#pragma unroll
    for (int i = 0; i < 4; ++i) aoffs[i] = (wm + i * 16 + frow) * BK;
#pragma unroll
    for (int j = 0; j < 4; ++j) boffs[j] = (wn + j * 16 + frow) * BK;

    floatx4 acc[4][4];
#pragma unroll
    for (int i = 0; i < 4; ++i)
#pragma unroll
        for (int j = 0; j < 4; ++j)
            acc[i][j] = floatx4{0.f, 0.f, 0.f, 0.f};

    STAGE(0, 0);
    STAGE(1, 1);
    int cur = 0;
    for (int it = 0; it < NIT; ++it) {
        if (it < NIT - 1) asm volatile("s_waitcnt vmcnt(4)" ::: "memory");
        else              asm volatile("s_waitcnt vmcnt(0)" ::: "memory");
        __builtin_amdgcn_s_barrier();      // all waves' tile `it` staged
        const unsigned char* pa = &sA[cur][0];
        const unsigned char* pb = &sB[cur][0];
#pragma unroll
        for (int kk = 0; kk < 2; ++kk) {
            const int cof = kk ? cof1 : cof0;
            long long af[4], bf[4];
#pragma unroll
            for (int i = 0; i < 4; ++i)
                af[i] = *(const long long*)(pa + aoffs[i] + cof);
#pragma unroll
            for (int j = 0; j < 4; ++j)
                bf[j] = *(const long long*)(pb + boffs[j] + cof);
#pragma unroll
            for (int i = 0; i < 4; ++i)
#pragma unroll
                for (int j = 0; j < 4; ++j)
                    acc[i][j] = __builtin_amdgcn_mfma_f32_16x16x32_fp8_fp8(
                        af[i], bf[j], acc[i][j], 0, 0, 0);
        }
        __builtin_amdgcn_sched_barrier(0); // pin reads before the barrier
        __builtin_amdgcn_s_barrier();      // all waves done reading buf[cur]
        if (it + 2 < NIT) STAGE(cur, it + 2);
        cur ^= 1;
    }
#undef STAGE

    // Epilogue: per-row max/sumexp over this block's 128 columns.
    float lmax[4][4], lsum[4][4];
    for (int i = 0; i < 4; i++) {
        for (int r = 0; r < 4; r++) {
            float m = -INFINITY;
            for (int j = 0; j < 4; j++) m = fmaxf(m, acc[i][j][r] * LOGIT_SCALE);
            for (int off = 1; off < 16; off <<= 1) m = fmaxf(m, __shfl_xor(m, off));
            float s2 = 0.f;
            for (int j = 0; j < 4; j++) s2 += __expf(acc[i][j][r] * LOGIT_SCALE - m);
            for (int off = 1; off < 16; off <<= 1) s2 += __shfl_xor(s2, off);
            lmax[i][r] = m; lsum[i][r] = s2;
        }
    }
    if ((lane & 15) == 0) {
        int lg = lane >> 4;
        for (int i = 0; i < 4; i++)
            for (int r = 0; r < 4; r++) {
                int row = wm + i * 16 + lg * 4 + r;
                pmax[wave >> 1][row] = lmax[i][r];
                psum[wave >> 1][row] = lsum[i][r];
            }
    }
    __syncthreads();
    if (t < TILE) {
        float ma = pmax[0][t], mb = pmax[1][t];
        float M = fmaxf(ma, mb);
        float Sv = psum[0][t] * __expf(ma - M) + psum[1][t] * __expf(mb - M);
        int grow = m0 + t;
        part_max[(size_t)grow * NT + bn] = M;
        part_sum[(size_t)grow * NT + bn] = Sv;
    }
}

// ---------------------------------------------------------------------------
// Loss: one wave per row. Label logit from ll[] (ws path) or exact gather-dot
// (fallback). LSE over the 128 tile partials + mean-NLL atomicAdd.
// ---------------------------------------------------------------------------
__global__ __launch_bounds__(256) void loss_kernel(
    const float* __restrict__ X, const float* __restrict__ S,
    const int* __restrict__ labels,
    const float* __restrict__ part_max, const float* __restrict__ part_sum,
    const float* __restrict__ ll_in, float* __restrict__ out0) {
    const int wave = threadIdx.x >> 6, lane = threadIdx.x & 63;
    const int row = blockIdx.x * 4 + wave;
    float ll;
    if (ll_in) {
        ll = ll_in[row];
    } else {
        const float4* x4 = (const float4*)(X + (size_t)row * D_N);
        const float4* s4 = (const float4*)(S + (size_t)labels[row] * D_N);
        float acc = 0.f;
        for (int k = lane; k < D_N / 4; k += 64) {
            float4 a = x4[k], bb = s4[k];
            acc += a.x * bb.x + a.y * bb.y + a.z * bb.z + a.w * bb.w;
        }
        for (int off = 32; off; off >>= 1) acc += __shfl_xor(acc, off);
        ll = acc * TEMP_INV;
    }
    const float* pm = part_max + (size_t)row * NT;
    const float* ps = part_sum + (size_t)row * NT;
    float m1 = pm[lane], m2 = pm[lane + 64];
    float M = fmaxf(m1, m2);
    for (int off = 32; off; off >>= 1) M = fmaxf(M, __shfl_xor(M, off));
    float Sv = ps[lane] * __expf(m1 - M) + ps[lane + 64] * __expf(m2 - M);
    for (int off = 32; off; off >>= 1) Sv += __shfl_xor(Sv, off);
    float v = ll - (M + __logf(Sv));
    __shared__ float red[4];
    if (lane == 0) red[wave] = v;
    __syncthreads();
    if (threadIdx.x == 0)
        atomicAdd(out0, -(red[0] + red[1] + red[2] + red[3]) * (1.0f / (float)B_N));
}

extern "C" void kernel_launch(void* const* d_in, const int* in_sizes, int n_in,
                              void* d_out, int out_size, void* d_ws, size_t ws_size,
                              hipStream_t stream) {
    const float* X = (const float*)d_in[0];       // (1024, 2048)
    const float* S = (const float*)d_in[1];       // (16384, 2048)
    const int* labels = (const int*)d_in[4];      // abs_proxy_labels (1024)
    float* out = (float*)d_out;                   // [loss, new_storage...]

    const size_t sf8_bytes = (size_t)P_N * D_N;            // 33,554,432
    const size_t xf8_bytes = (size_t)B_N * D_N;            //  2,097,152
    const size_t need = sf8_bytes + xf8_bytes + (size_t)B_N * NT * 8
                        + (size_t)B_N * 4 + 64;
    const bool use_ws = (ws_size >= need);

    unsigned char* scratch = use_ws ? (unsigned char*)d_ws
                                    : (unsigned char*)d_out + 16;
    unsigned char* Sf8 = scratch;
    unsigned char* Xf8 = scratch + sf8_bytes;
    float* part_max = (float*)(Xf8 + xf8_bytes);
    float* part_sum = part_max + (size_t)B_N * NT;
    float* ll = part_sum + (size_t)B_N * NT;

    // 1. Streaming fp8 convert + aligned-quad fp32 storage copy (ws path).
    stream_convert_kernel<<<2048, 256, 0, stream>>>(
        X, S, Xf8, Sf8, out, use_ws ? out : nullptr);
    // 2. Chain-walk EMA update (overwrites copied rows); computes ll.
    if (use_ws)
        update_kernel<<<B_N, 256, 0, stream>>>(X, S, labels, out + 1, ll);
    // 3. fp8 GEMM + fused per-tile softmax partials.
    gemm_softmax_kernel<<<1024, 256, 0, stream>>>(Xf8, Sf8, part_max, part_sum);
    // 4. LSE + mean-NLL.
    loss_kernel<<<256, 256, 0, stream>>>(X, S, labels, part_max, part_sum,
                                         use_ws ? ll : nullptr, out);
    if (!use_ws)  // scratch lived inside out: write storage rows now
        update_copy_kernel<<<P_N, 256, 0, stream>>>(X, S, labels, out + 1);
}